// Round 1
// baseline (1021.978 us; speedup 1.0000x reference)
//
#include <hip/hip_runtime.h>

// Problem geometry (fixed by the reference): in[32][224][224][128] f32, out[32][128] f32.
constexpr int B = 32;
constexpr int S = 224 * 224;        // 50176 spatial positions per batch
constexpr int C = 128;              // channels, innermost (stride 1)
constexpr int CQ = C / 4;           // 32 float4 quads per position
constexpr int NCHUNK = 64;          // spatial chunks per batch -> 32*64 = 2048 blocks
constexpr int CHUNK = S / NCHUNK;   // 784 positions per block (exact)
constexpr int BLOCK = 256;
constexpr int GROUPS = BLOCK / CQ;  // 8 positions read concurrently per block

__device__ inline void fmax4(float4& a, const float4& b) {
    a.x = fmaxf(a.x, b.x);
    a.y = fmaxf(a.y, b.y);
    a.z = fmaxf(a.z, b.z);
    a.w = fmaxf(a.w, b.w);
}

// Stage 1: each block reduces CHUNK positions of one (batch, chunk) to a
// partial max[128], written to ws[blk][128].
__global__ __launch_bounds__(BLOCK) void partial_max_kernel(
        const float* __restrict__ in, float* __restrict__ part) {
    const int blk   = blockIdx.x;        // b * NCHUNK + chunk
    const int b     = blk / NCHUNK;
    const int chunk = blk % NCHUNK;
    const int t  = threadIdx.x;
    const int g  = t >> 5;               // position-group 0..7
    const int cq = t & 31;               // channel-quad 0..31

    const float4* base = reinterpret_cast<const float4*>(in)
                       + ((size_t)b * S + (size_t)chunk * CHUNK) * CQ;

    float4 m = make_float4(-INFINITY, -INFINITY, -INFINITY, -INFINITY);
    // Block reads 8 consecutive positions (4 KB contiguous) per iteration.
    for (int p = g; p < CHUNK; p += GROUPS) {
        float4 v = base[(size_t)p * CQ + cq];
        fmax4(m, v);
    }

    __shared__ float4 lds[BLOCK];
    lds[t] = m;
    __syncthreads();

    if (t < CQ) {
        float4 r = lds[t];
        #pragma unroll
        for (int k = 1; k < GROUPS; ++k)
            fmax4(r, lds[t + k * CQ]);
        reinterpret_cast<float4*>(part)[(size_t)blk * CQ + t] = r;
    }
}

// Stage 2: fold the NCHUNK partials per (b, c). 32 blocks x 128 threads.
__global__ __launch_bounds__(C) void final_max_kernel(
        const float* __restrict__ part, float* __restrict__ out) {
    const int b = blockIdx.x;
    const int c = threadIdx.x;
    float m = -INFINITY;
    #pragma unroll 8
    for (int k = 0; k < NCHUNK; ++k)
        m = fmaxf(m, part[((size_t)b * NCHUNK + k) * C + c]);
    out[(size_t)b * C + c] = m;
}

extern "C" void kernel_launch(void* const* d_in, const int* in_sizes, int n_in,
                              void* d_out, int out_size, void* d_ws, size_t ws_size,
                              hipStream_t stream) {
    const float* in = (const float*)d_in[0];
    float* out = (float*)d_out;
    float* part = (float*)d_ws;   // needs B*NCHUNK*C*4 = 1 MiB

    partial_max_kernel<<<B * NCHUNK, BLOCK, 0, stream>>>(in, part);
    final_max_kernel<<<B, C, 0, stream>>>(part, out);
}